// Round 11
// baseline (751.181 us; speedup 1.0000x reference)
//
#include <hip/hip_runtime.h>
#include <hip/hip_bf16.h>

// NNConv GNN, round 11 — eks via LDS staging (kill the scalar-cache path):
//  R7-R10 evidence: per-slot eks loads through K$ (s_load) or per-lane VMEM
//  are the bottleneck (~70-100 us with all pipes idle; occupancy doubling
//  made it WORSE via K$ thrash). Fix: block's slot range is contiguous ->
//  cooperatively stage eks rows + ss2sd into LDS (coalesced f32x4), combine
//  reads them as wave-uniform ds_read_b128 broadcasts.
//  Structure: 512-thread blocks, TM=8 nodes, Pt=34.9KB + staging 4.3KB ->
//  4 blocks/CU. MFMA P->LDS (+Proot->global), then per-wave contiguous slot
//  sub-ranges, P row register-cached per node, msg scattered to dst-CSR
//  order so agg streams coalesced.

#define NN 20000
#define NE 100000
#define WD 64
#define DEPTH 6
#define TM 8             // nodes per tile
#define LSTR 1092        // LDS row stride (words): 1092%32==4 -> 2-way only
#define CH 64            // eks staging chunk (slots)

typedef __attribute__((ext_vector_type(8))) short bf16x8;
typedef __attribute__((ext_vector_type(4))) float f32x4;

__device__ __forceinline__ unsigned short f2bf(float v) {
    union { float f; unsigned u; } x; x.f = v;
    unsigned r = x.u + 0x7fffu + ((x.u >> 16) & 1u);
    return (unsigned short)(r >> 16);
}
__device__ __forceinline__ float bf2f(unsigned short b) {
    union { unsigned u; float f; } x; x.u = ((unsigned)b) << 16;
    return x.f;
}

// ---------------- per-node in/out degree counts ----------------
__global__ __launch_bounds__(256) void count_kernel(const int* __restrict__ ei,
                                                    int* __restrict__ outc,
                                                    int* __restrict__ inc)
{
    int e = blockIdx.x * 256 + threadIdx.x;
    if (e >= NE) return;
    atomicAdd(&outc[ei[e]], 1);
    atomicAdd(&inc[ei[NE + e]], 1);
}

// ---------------- hierarchical scan over [outc | inc] (40000 ints) ----------
__global__ __launch_bounds__(256) void scanA_kernel(const int* __restrict__ cnt,
                                                    int* __restrict__ partials)
{
    int b = blockIdx.x, t = threadIdx.x, lane = t & 63, w = t >> 6;
    int base = b * 1024 + t * 4;
    int s = 0;
#pragma unroll
    for (int i = 0; i < 4; ++i) {
        int idx = base + i;
        if (idx < 2 * NN) s += cnt[idx];
    }
#pragma unroll
    for (int off = 32; off > 0; off >>= 1) s += __shfl_down(s, off, 64);
    __shared__ int wsum[4];
    if (lane == 0) wsum[w] = s;
    __syncthreads();
    if (t == 0) partials[b] = wsum[0] + wsum[1] + wsum[2] + wsum[3];
}

__global__ __launch_bounds__(64) void scanB_kernel(const int* __restrict__ partials,
                                                   int* __restrict__ bases)
{
    int l = threadIdx.x;
    int p = (l < 40) ? partials[l] : 0;
    int v = p;
#pragma unroll
    for (int off = 1; off < 64; off <<= 1) {
        int u = __shfl_up(v, off, 64);
        if (l >= off) v += u;
    }
    if (l < 40) bases[l] = v - p;   // exclusive
}

__global__ __launch_bounds__(256) void scanC_kernel(const int* __restrict__ cnt,
                                                    const int* __restrict__ bases,
                                                    int* __restrict__ rps,
                                                    int* __restrict__ rpd,
                                                    float* __restrict__ invd)
{
    int b = blockIdx.x, t = threadIdx.x, lane = t & 63, w = t >> 6;
    int base = b * 1024 + t * 4;
    int v[4], s = 0;
#pragma unroll
    for (int i = 0; i < 4; ++i) {
        int idx = base + i;
        v[i] = (idx < 2 * NN) ? cnt[idx] : 0;
        s += v[i];
    }
    int tsum = s, sc = s;
#pragma unroll
    for (int off = 1; off < 64; off <<= 1) {
        int u = __shfl_up(sc, off, 64);
        if (lane >= off) sc += u;
    }
    __shared__ int wtot[4];
    if (lane == 63) wtot[w] = sc;
    __syncthreads();
    int wbase = 0;
    for (int j = 0; j < w; ++j) wbase += wtot[j];
    int run = bases[b] + wbase + sc - tsum;
#pragma unroll
    for (int i = 0; i < 4; ++i) {
        int idx = base + i;
        int e = run; run += v[i];
        if (idx < NN) {
            rps[idx] = e;
        } else if (idx < 2 * NN) {
            rpd[idx - NN] = e - NE;           // first-half total == NE
            invd[idx - NN] = 1.0f / fmaxf((float)v[i], 1.0f);
        }
    }
    if (b == 0 && t == 0) { rps[NN] = NE; rpd[NN] = NE; }
}

// ---------------- ek MLP + CSR fill ----------------
__global__ __launch_bounds__(256) void ekfill_kernel(
    const int* __restrict__ ei, const float* __restrict__ ea,
    const float* __restrict__ k1w, const float* __restrict__ k1b,
    const int* __restrict__ rps, const int* __restrict__ rpd,
    int* __restrict__ fs, int* __restrict__ fd,
    float* __restrict__ eks, int* __restrict__ ss2sd)
{
    int e = blockIdx.x * 256 + threadIdx.x;
    if (e >= NE) return;
    int s = ei[e], d = ei[NE + e];
    float a[6];
#pragma unroll
    for (int i = 0; i < 6; ++i) a[i] = ea[e * 6 + i];
    int slot_s = rps[s] + atomicAdd(&fs[s], 1);
    int slot_d = rpd[d] + atomicAdd(&fd[d], 1);
    ss2sd[slot_s] = slot_d;
#pragma unroll
    for (int j = 0; j < 16; ++j) {
        float v = k1b[j];
#pragma unroll
        for (int i = 0; i < 6; ++i) v = fmaf(a[i], k1w[i * 16 + j], v);
        eks[(size_t)slot_s * 16 + j] = fmaxf(v, 0.f);
    }
}

// ---------------- GwT hi/lo bf16, [1152 rows n][64 cols k] -----------------
__global__ __launch_bounds__(256) void gwt_kernel(
    const float* __restrict__ k2w, const float* __restrict__ k2b,
    const float* __restrict__ rootw,
    unsigned short* __restrict__ Gh, unsigned short* __restrict__ Gl)
{
    int idx = blockIdx.x * 256 + threadIdx.x;   // 1152*64
    if (idx >= 1152 * 64) return;
    int n = idx >> 6, k = idx & 63;
    int b = n >> 6, o = n & 63;
    float g;
    if (b < 16)       g = k2w[b * 4096 + k * 64 + o];
    else if (b == 16) g = k2b[k * 64 + o];
    else              g = rootw[k * 64 + o];
    unsigned short hi = f2bf(g);
    Gh[idx] = hi;
    Gl[idx] = f2bf(g - bf2f(hi));
}

// ---------------- h0 = x*fc1_w + fc1_b -> hi/lo bf16 ----------------
__global__ __launch_bounds__(256) void h0_kernel(
    const float* __restrict__ x, const float* __restrict__ w,
    const float* __restrict__ b,
    unsigned short* __restrict__ hhi, unsigned short* __restrict__ hlo)
{
    int idx = blockIdx.x * 256 + threadIdx.x;
    if (idx >= NN * WD) return;
    int n = idx >> 6, o = idx & 63;
    float v = fmaf(x[n], w[o], b[o]);
    unsigned short hi = f2bf(v);
    hhi[idx] = hi;
    hlo[idx] = f2bf(v - bf2f(hi));
}

// ---------------- fused: MFMA P->LDS (+Proot->global), then edge combine ----
__global__ __launch_bounds__(512, 8) void fused_kernel(
    const unsigned short* __restrict__ hhi, const unsigned short* __restrict__ hlo,
    const unsigned short* __restrict__ Gh, const unsigned short* __restrict__ Gl,
    const float* __restrict__ eks, const int* __restrict__ ss2sd,
    const int* __restrict__ rps, float* __restrict__ Proot,
    float* __restrict__ msg)
{
    __shared__ __align__(16) float Pt[TM * LSTR];    // 34,944 B
    __shared__ __align__(16) float eksh[CH * 16];    // 4,096 B
    __shared__ int sdh[CH];                          // 256 B
    __shared__ int rb[TM + 1];
    int n0 = blockIdx.x * TM;
    int w = threadIdx.x >> 6, l = threadIdx.x & 63;
    int quad = l >> 4, lr = l & 15;
    if (threadIdx.x < TM + 1) {
        int gi = n0 + threadIdx.x;
        rb[threadIdx.x] = rps[gi > NN ? NN : gi];
    }
    int arow = n0 + lr;
    if (arow > NN - 1) arow = NN - 1;
    const bf16x8* pah = (const bf16x8*)(hhi + (size_t)arow * 64 + quad * 8);
    const bf16x8* pal = (const bf16x8*)(hlo + (size_t)arow * 64 + quad * 8);
    bf16x8 ah0 = pah[0], ah1 = pah[4];   // k 0..31, 32..63
    bf16x8 al0 = pal[0], al1 = pal[4];

    // tile-by-tile MFMA (single f32x4 acc) to keep VGPR pressure low
    for (int st = w; st < 18; st += 8) {
#pragma unroll
        for (int t = 0; t < 4; ++t) {
            int brow = st * 64 + t * 16 + lr;
            f32x4 a = (f32x4){0.f, 0.f, 0.f, 0.f};
            {
                const bf16x8* pbh = (const bf16x8*)(Gh + (size_t)brow * 64 + quad * 8);
                const bf16x8* pbl = (const bf16x8*)(Gl + (size_t)brow * 64 + quad * 8);
                bf16x8 bh0 = pbh[0], bl0 = pbl[0];
                a = __builtin_amdgcn_mfma_f32_16x16x32_bf16(ah0, bh0, a, 0, 0, 0);
                a = __builtin_amdgcn_mfma_f32_16x16x32_bf16(ah0, bl0, a, 0, 0, 0);
                a = __builtin_amdgcn_mfma_f32_16x16x32_bf16(al0, bh0, a, 0, 0, 0);
            }
            {
                const bf16x8* pbh = (const bf16x8*)(Gh + (size_t)brow * 64 + 32 + quad * 8);
                const bf16x8* pbl = (const bf16x8*)(Gl + (size_t)brow * 64 + 32 + quad * 8);
                bf16x8 bh1 = pbh[0], bl1 = pbl[0];
                a = __builtin_amdgcn_mfma_f32_16x16x32_bf16(ah1, bh1, a, 0, 0, 0);
                a = __builtin_amdgcn_mfma_f32_16x16x32_bf16(ah1, bl1, a, 0, 0, 0);
                a = __builtin_amdgcn_mfma_f32_16x16x32_bf16(al1, bh1, a, 0, 0, 0);
            }
            // C/D layout: col = lane&15, row = quad*4 + reg
            if (st < 17) {
#pragma unroll
                for (int r = 0; r < 4; ++r) {
                    int row = quad * 4 + r;
                    if (row < TM)
                        Pt[row * LSTR + st * 64 + t * 16 + lr] = a[r];
                }
            } else {
#pragma unroll
                for (int r = 0; r < 4; ++r) {
                    int row = quad * 4 + r;
                    int gn = n0 + row;
                    if (row < TM && gn < NN)
                        Proot[(size_t)gn * 64 + t * 16 + lr] = a[r];
                }
            }
        }
    }

    // edge phase, chunked LDS staging of eks/ss2sd
    int nend = n0 + TM; if (nend > NN) nend = NN;
    int tmeff = nend - n0;
    __syncthreads();                       // Pt + rb ready
    int r0 = rb[0], r1 = rb[tmeff];
    int total = r1 - r0;
    if (total <= 0) return;                // block-uniform: safe
    int per = (total + 7) >> 3;
    int s0 = r0 + w * per;
    int s1 = s0 + per; if (s1 > r1) s1 = r1;

    for (int c0 = r0; c0 < r1; c0 += CH) {
        int cend = c0 + CH; if (cend > r1) cend = r1;
        int cnt = cend - c0;
        __syncthreads();                   // previous chunk consumed
        {   // stage eks rows (f32x4-coalesced) + ss2sd
            const f32x4* src = (const f32x4*)(eks + (size_t)c0 * 16);
            f32x4* dst = (f32x4*)eksh;
            for (int i = threadIdx.x; i < cnt * 4; i += 512) dst[i] = src[i];
            for (int i = threadIdx.x; i < cnt; i += 512) sdh[i] = ss2sd[c0 + i];
        }
        __syncthreads();
        int lo = s0 > c0 ? s0 : c0;
        int hi = s1 < cend ? s1 : cend;
        if (lo >= hi) continue;
        for (int ln = 0; ln < tmeff && lo < hi; ++ln) {
            int nlo = lo > rb[ln] ? lo : rb[ln];
            int nhi = hi < rb[ln + 1] ? hi : rb[ln + 1];
            if (nlo >= nhi) continue;
            float p[17];
            const float* Pr = &Pt[ln * LSTR];
#pragma unroll
            for (int k = 0; k < 17; ++k) p[k] = Pr[k * 64 + l];
            for (int s = nlo; s < nhi; ++s) {
                int si = s - c0;
                const f32x4* er = (const f32x4*)&eksh[si * 16];
                f32x4 e0 = er[0], e1 = er[1], e2 = er[2], e3 = er[3];
                int ds = sdh[si];
                float ma = p[16], mb = 0.f;   // two chains for ILP
                ma = fmaf(e0[0], p[0], ma);  mb = fmaf(e0[1], p[1], mb);
                ma = fmaf(e0[2], p[2], ma);  mb = fmaf(e0[3], p[3], mb);
                ma = fmaf(e1[0], p[4], ma);  mb = fmaf(e1[1], p[5], mb);
                ma = fmaf(e1[2], p[6], ma);  mb = fmaf(e1[3], p[7], mb);
                ma = fmaf(e2[0], p[8], ma);  mb = fmaf(e2[1], p[9], mb);
                ma = fmaf(e2[2], p[10], ma); mb = fmaf(e2[3], p[11], mb);
                ma = fmaf(e3[0], p[12], ma); mb = fmaf(e3[1], p[13], mb);
                ma = fmaf(e3[2], p[14], ma); mb = fmaf(e3[3], p[15], mb);
                msg[(size_t)ds * 64 + l] = ma + mb;
            }
            lo = nhi;
        }
    }
}

// ---------------- per-dst sum (coalesced, 4-way ILP) + fused epilogue -------
__global__ __launch_bounds__(256) void agg_kernel(
    const float* __restrict__ msg, const int* __restrict__ rpd,
    const float* __restrict__ invd, const float* __restrict__ Proot,
    const float* __restrict__ convb, float* __restrict__ h,
    unsigned short* __restrict__ hhi, unsigned short* __restrict__ hlo)
{
    int i = blockIdx.x * 4 + (threadIdx.x >> 6);
    if (i >= NN) return;
    int l = threadIdx.x & 63;
    int r0 = rpd[i], r1 = rpd[i + 1];
    float a0 = 0.f, a1 = 0.f, a2 = 0.f, a3 = 0.f;
    int s = r0;
    for (; s + 3 < r1; s += 4) {
        a0 += msg[(size_t)s * 64 + l];
        a1 += msg[(size_t)(s + 1) * 64 + l];
        a2 += msg[(size_t)(s + 2) * 64 + l];
        a3 += msg[(size_t)(s + 3) * 64 + l];
    }
    for (; s < r1; ++s) a0 += msg[(size_t)s * 64 + l];
    float acc = (a0 + a1) + (a2 + a3);
    float v = fmaf(acc, invd[i], Proot[(size_t)i * 64 + l] + convb[l]);
    v = fmaxf(v, 0.f);
    int idx = i * 64 + l;
    h[idx] = v;
    unsigned short hi = f2bf(v);
    hhi[idx] = hi;
    hlo[idx] = f2bf(v - bf2f(hi));
}

// ---------------- out = h @ fc2_w + fc2_b ----------------
__global__ __launch_bounds__(256) void out_kernel(
    const float* __restrict__ h, const float* __restrict__ fc2_w,
    const float* __restrict__ fc2_b, float* __restrict__ out)
{
    int wave = blockIdx.x * 4 + (threadIdx.x >> 6);
    int lane = threadIdx.x & 63;
    float v = h[(size_t)wave * 64 + lane] * fc2_w[lane];
#pragma unroll
    for (int off = 32; off > 0; off >>= 1) v += __shfl_down(v, off);
    if (lane == 0) out[wave] = v + fc2_b[0];
}

extern "C" void kernel_launch(void* const* d_in, const int* in_sizes, int n_in,
                              void* d_out, int out_size, void* d_ws, size_t ws_size,
                              hipStream_t stream)
{
    const float* x         = (const float*)d_in[0];
    const int*   ei        = (const int*)  d_in[1];
    const float* edge_attr = (const float*)d_in[2];
    const float* fc1_w     = (const float*)d_in[3];
    const float* fc1_b     = (const float*)d_in[4];
    const float* k1_w      = (const float*)d_in[5];
    const float* k1_b      = (const float*)d_in[6];
    const float* k2_w      = (const float*)d_in[7];
    const float* k2_b      = (const float*)d_in[8];
    const float* root_w    = (const float*)d_in[9];
    const float* conv_b    = (const float*)d_in[10];
    const float* fc2_w     = (const float*)d_in[11];
    const float* fc2_b     = (const float*)d_in[12];
    float* out = (float*)d_out;

    // workspace layout, f32 units
    float* ws = (float*)d_ws;
    size_t off = 0;
    int* cnt   = (int*)(ws + off); off += 4 * NN;       // outc|inc|fs|fd
    int* outc  = cnt;
    int* inc   = cnt + NN;
    int* fs    = cnt + 2 * NN;
    int* fd    = cnt + 3 * NN;
    int* rps   = (int*)(ws + off); off += 20004;
    int* rpd   = (int*)(ws + off); off += 20004;
    int* partials = (int*)(ws + off); off += 64;
    int* bases    = (int*)(ws + off); off += 64;
    int* ss2sd    = (int*)(ws + off); off += NE;
    float* invd  = ws + off; off += NN;
    float* eks   = ws + off; off += (size_t)NE * 16;
    unsigned short* Gh  = (unsigned short*)(ws + off); off += 36864;
    unsigned short* Gl  = (unsigned short*)(ws + off); off += 36864;
    unsigned short* hhi = (unsigned short*)(ws + off); off += (size_t)NN * 32;
    unsigned short* hlo = (unsigned short*)(ws + off); off += (size_t)NN * 32;
    float* h     = ws + off; off += (size_t)NN * WD;
    float* msg   = ws + off; off += (size_t)NE * WD;
    float* Proot = ws + off; off += (size_t)NN * WD;

    hipMemsetAsync(cnt, 0, 4 * NN * sizeof(int), stream);
    count_kernel<<<(NE + 255) / 256, 256, 0, stream>>>(ei, outc, inc);
    scanA_kernel<<<40, 256, 0, stream>>>(cnt, partials);
    scanB_kernel<<<1, 64, 0, stream>>>(partials, bases);
    scanC_kernel<<<40, 256, 0, stream>>>(cnt, bases, rps, rpd, invd);
    ekfill_kernel<<<(NE + 255) / 256, 256, 0, stream>>>(ei, edge_attr, k1_w, k1_b,
                                                        rps, rpd, fs, fd, eks, ss2sd);
    gwt_kernel<<<(1152 * 64 + 255) / 256, 256, 0, stream>>>(k2_w, k2_b, root_w, Gh, Gl);
    h0_kernel<<<(NN * WD + 255) / 256, 256, 0, stream>>>(x, fc1_w, fc1_b, hhi, hlo);

    int ntiles = (NN + TM - 1) / TM;   // 2500
    for (int layer = 0; layer < DEPTH; ++layer) {
        fused_kernel<<<ntiles, 512, 0, stream>>>(hhi, hlo, Gh, Gl, eks, ss2sd,
                                                 rps, Proot, msg);
        agg_kernel<<<(NN + 3) / 4, 256, 0, stream>>>(msg, rpd, invd, Proot,
                                                     conv_b, h, hhi, hlo);
    }

    out_kernel<<<NN / 4, 256, 0, stream>>>(h, fc2_w, fc2_b, out);
}

// Round 12
// 569.026 us; speedup vs baseline: 1.3201x; 1.3201x over previous
//
#include <hip/hip_runtime.h>
#include <hip/hip_bf16.h>

// NNConv GNN, round 12 — R7 base + traffic/launch elimination:
//  Per layer ONE fused kernel (512 thr, TM=15 tile, 2 blocks/CU):
//   prologue: build this layer's h for the tile IN-REGISTER from last layer's
//     agg/Proot (mean/root/bias/relu epilogue fused here; layer 0 builds from
//     x*fc1_w+fc1_b) -> split-bf16 A fragments.
//   GEMM: P_tile = h @ [K_0..K_15|Bmat] via split-bf16 MFMA into LDS
//     (65.5 KB, never HBM); strip 17 -> ProotOut (ping-pong).
//   edge phase: per-wave contiguous src-CSR slot sub-ranges, P row register-
//     cached per node, scalar eks/dst loads, atomicAdd direct into aggOut
//     (ping-pong) — msg buffer + agg kernel + h/hhi/hlo buffers all deleted.
//  out_kernel applies the final epilogue + fc2 dot.
//  CSR built per call: count -> hierarchical 3-kernel scan -> fill.

#define NN 20000
#define NE 100000
#define WD 64
#define DEPTH 6
#define TM 15            // nodes per tile (MFMA row 15 wasted)
#define LSTR 1092        // LDS row stride (words): 1092%32==4 -> 2-way only

typedef __attribute__((ext_vector_type(8))) short bf16x8;
typedef __attribute__((ext_vector_type(4))) float f32x4;

__device__ __forceinline__ unsigned short f2bf(float v) {
    union { float f; unsigned u; } x; x.f = v;
    unsigned r = x.u + 0x7fffu + ((x.u >> 16) & 1u);
    return (unsigned short)(r >> 16);
}
__device__ __forceinline__ float bf2f(unsigned short b) {
    union { unsigned u; float f; } x; x.u = ((unsigned)b) << 16;
    return x.f;
}

// ---------------- per-node in/out degree counts ----------------
__global__ __launch_bounds__(256) void count_kernel(const int* __restrict__ ei,
                                                    int* __restrict__ outc,
                                                    int* __restrict__ inc)
{
    int e = blockIdx.x * 256 + threadIdx.x;
    if (e >= NE) return;
    atomicAdd(&outc[ei[e]], 1);
    atomicAdd(&inc[ei[NE + e]], 1);
}

// ---------------- hierarchical scan over [outc | inc] (40000 ints) ----------
__global__ __launch_bounds__(256) void scanA_kernel(const int* __restrict__ cnt,
                                                    int* __restrict__ partials)
{
    int b = blockIdx.x, t = threadIdx.x, lane = t & 63, w = t >> 6;
    int base = b * 1024 + t * 4;
    int s = 0;
#pragma unroll
    for (int i = 0; i < 4; ++i) {
        int idx = base + i;
        if (idx < 2 * NN) s += cnt[idx];
    }
#pragma unroll
    for (int off = 32; off > 0; off >>= 1) s += __shfl_down(s, off, 64);
    __shared__ int wsum[4];
    if (lane == 0) wsum[w] = s;
    __syncthreads();
    if (t == 0) partials[b] = wsum[0] + wsum[1] + wsum[2] + wsum[3];
}

__global__ __launch_bounds__(64) void scanB_kernel(const int* __restrict__ partials,
                                                   int* __restrict__ bases)
{
    int l = threadIdx.x;
    int p = (l < 40) ? partials[l] : 0;
    int v = p;
#pragma unroll
    for (int off = 1; off < 64; off <<= 1) {
        int u = __shfl_up(v, off, 64);
        if (l >= off) v += u;
    }
    if (l < 40) bases[l] = v - p;   // exclusive
}

__global__ __launch_bounds__(256) void scanC_kernel(const int* __restrict__ cnt,
                                                    const int* __restrict__ bases,
                                                    int* __restrict__ rps,
                                                    float* __restrict__ invd)
{
    int b = blockIdx.x, t = threadIdx.x, lane = t & 63, w = t >> 6;
    int base = b * 1024 + t * 4;
    int v[4], s = 0;
#pragma unroll
    for (int i = 0; i < 4; ++i) {
        int idx = base + i;
        v[i] = (idx < 2 * NN) ? cnt[idx] : 0;
        s += v[i];
    }
    int tsum = s, sc = s;
#pragma unroll
    for (int off = 1; off < 64; off <<= 1) {
        int u = __shfl_up(sc, off, 64);
        if (lane >= off) sc += u;
    }
    __shared__ int wtot[4];
    if (lane == 63) wtot[w] = sc;
    __syncthreads();
    int wbase = 0;
    for (int j = 0; j < w; ++j) wbase += wtot[j];
    int run = bases[b] + wbase + sc - tsum;
#pragma unroll
    for (int i = 0; i < 4; ++i) {
        int idx = base + i;
        int e = run; run += v[i];
        if (idx < NN) {
            rps[idx] = e;
        } else if (idx < 2 * NN) {
            invd[idx - NN] = 1.0f / fmaxf((float)v[i], 1.0f);
        }
    }
    if (b == 0 && t == 0) rps[NN] = NE;
}

// ---------------- ek MLP + src-CSR fill (dst node id per slot) --------------
__global__ __launch_bounds__(256) void ekfill_kernel(
    const int* __restrict__ ei, const float* __restrict__ ea,
    const float* __restrict__ k1w, const float* __restrict__ k1b,
    const int* __restrict__ rps, int* __restrict__ fs,
    float* __restrict__ eks, int* __restrict__ dsts)
{
    int e = blockIdx.x * 256 + threadIdx.x;
    if (e >= NE) return;
    int s = ei[e], d = ei[NE + e];
    float a[6];
#pragma unroll
    for (int i = 0; i < 6; ++i) a[i] = ea[e * 6 + i];
    int slot_s = rps[s] + atomicAdd(&fs[s], 1);
    dsts[slot_s] = d;
#pragma unroll
    for (int j = 0; j < 16; ++j) {
        float v = k1b[j];
#pragma unroll
        for (int i = 0; i < 6; ++i) v = fmaf(a[i], k1w[i * 16 + j], v);
        eks[(size_t)slot_s * 16 + j] = fmaxf(v, 0.f);
    }
}

// ---------------- GwT hi/lo bf16, [1152 rows n][64 cols k] -----------------
__global__ __launch_bounds__(256) void gwt_kernel(
    const float* __restrict__ k2w, const float* __restrict__ k2b,
    const float* __restrict__ rootw,
    unsigned short* __restrict__ Gh, unsigned short* __restrict__ Gl)
{
    int idx = blockIdx.x * 256 + threadIdx.x;   // 1152*64
    if (idx >= 1152 * 64) return;
    int n = idx >> 6, k = idx & 63;
    int b = n >> 6, o = n & 63;
    float g;
    if (b < 16)       g = k2w[b * 4096 + k * 64 + o];
    else if (b == 16) g = k2b[k * 64 + o];
    else              g = rootw[k * 64 + o];
    unsigned short hi = f2bf(g);
    Gh[idx] = hi;
    Gl[idx] = f2bf(g - bf2f(hi));
}

// ---------------- fused layer kernel ----------------
__global__ __launch_bounds__(512, 4) void fused_kernel(
    const float* __restrict__ x, const float* __restrict__ fc1w,
    const float* __restrict__ fc1b,
    const float* __restrict__ aggIn, const float* __restrict__ ProotIn,
    const float* __restrict__ invd, const float* __restrict__ convb,
    const unsigned short* __restrict__ Gh, const unsigned short* __restrict__ Gl,
    const float* __restrict__ eks, const int* __restrict__ dsts,
    const int* __restrict__ rps,
    float* __restrict__ ProotOut, float* __restrict__ aggOut, int first)
{
    __shared__ __align__(16) float Pt[TM * LSTR];   // 65,520 B
    __shared__ int rb[TM + 1];
    int n0 = blockIdx.x * TM;
    int w = threadIdx.x >> 6, l = threadIdx.x & 63;
    int quad = l >> 4, lr = l & 15;
    if (threadIdx.x < TM + 1) {
        int gi = n0 + threadIdx.x;
        rb[threadIdx.x] = rps[gi > NN ? NN : gi];
    }
    int arow = n0 + lr;
    if (arow > NN - 1) arow = NN - 1;

    // ---- A-fragment build: this layer's h row in-register ----
    // lane covers k = quad*8..quad*8+7 (frag 0) and +32 (frag 1)
    bf16x8 ah0, al0, ah1, al1;
    if (first) {
        float xv = x[arow];
#pragma unroll
        for (int half = 0; half < 2; ++half) {
            int kb = half * 32 + quad * 8;
            f32x4 w0 = *(const f32x4*)(fc1w + kb);
            f32x4 w1 = *(const f32x4*)(fc1w + kb + 4);
            f32x4 b0 = *(const f32x4*)(fc1b + kb);
            f32x4 b1 = *(const f32x4*)(fc1b + kb + 4);
#pragma unroll
            for (int j = 0; j < 4; ++j) {
                float v0 = fmaf(xv, w0[j], b0[j]);
                float v1 = fmaf(xv, w1[j], b1[j]);
                unsigned short h0 = f2bf(v0), h1 = f2bf(v1);
                if (half == 0) {
                    ah0[j] = (short)h0;     al0[j] = (short)f2bf(v0 - bf2f(h0));
                    ah0[4 + j] = (short)h1; al0[4 + j] = (short)f2bf(v1 - bf2f(h1));
                } else {
                    ah1[j] = (short)h0;     al1[j] = (short)f2bf(v0 - bf2f(h0));
                    ah1[4 + j] = (short)h1; al1[4 + j] = (short)f2bf(v1 - bf2f(h1));
                }
            }
        }
    } else {
        float iv = invd[arow];
        size_t rbase = (size_t)arow * 64;
#pragma unroll
        for (int half = 0; half < 2; ++half) {
            int kb = half * 32 + quad * 8;
            f32x4 g0 = *(const f32x4*)(aggIn + rbase + kb);
            f32x4 g1 = *(const f32x4*)(aggIn + rbase + kb + 4);
            f32x4 p0 = *(const f32x4*)(ProotIn + rbase + kb);
            f32x4 p1 = *(const f32x4*)(ProotIn + rbase + kb + 4);
            f32x4 c0 = *(const f32x4*)(convb + kb);
            f32x4 c1 = *(const f32x4*)(convb + kb + 4);
#pragma unroll
            for (int j = 0; j < 4; ++j) {
                float v0 = fmaxf(fmaf(g0[j], iv, p0[j] + c0[j]), 0.f);
                float v1 = fmaxf(fmaf(g1[j], iv, p1[j] + c1[j]), 0.f);
                unsigned short h0 = f2bf(v0), h1 = f2bf(v1);
                if (half == 0) {
                    ah0[j] = (short)h0;     al0[j] = (short)f2bf(v0 - bf2f(h0));
                    ah0[4 + j] = (short)h1; al0[4 + j] = (short)f2bf(v1 - bf2f(h1));
                } else {
                    ah1[j] = (short)h0;     al1[j] = (short)f2bf(v0 - bf2f(h0));
                    ah1[4 + j] = (short)h1; al1[4 + j] = (short)f2bf(v1 - bf2f(h1));
                }
            }
        }
    }

    // ---- GEMM: 18 strips spread over 8 waves ----
    for (int st = w; st < 18; st += 8) {
        f32x4 acc[4];
#pragma unroll
        for (int t = 0; t < 4; ++t) acc[t] = (f32x4){0.f, 0.f, 0.f, 0.f};
#pragma unroll
        for (int t = 0; t < 4; ++t) {
            int brow = st * 64 + t * 16 + lr;
            const bf16x8* pbh = (const bf16x8*)(Gh + (size_t)brow * 64 + quad * 8);
            const bf16x8* pbl = (const bf16x8*)(Gl + (size_t)brow * 64 + quad * 8);
            bf16x8 bh0 = pbh[0], bh1 = pbh[4];
            bf16x8 bl0 = pbl[0], bl1 = pbl[4];
            f32x4 a = acc[t];
            a = __builtin_amdgcn_mfma_f32_16x16x32_bf16(ah0, bh0, a, 0, 0, 0);
            a = __builtin_amdgcn_mfma_f32_16x16x32_bf16(ah0, bl0, a, 0, 0, 0);
            a = __builtin_amdgcn_mfma_f32_16x16x32_bf16(al0, bh0, a, 0, 0, 0);
            a = __builtin_amdgcn_mfma_f32_16x16x32_bf16(ah1, bh1, a, 0, 0, 0);
            a = __builtin_amdgcn_mfma_f32_16x16x32_bf16(ah1, bl1, a, 0, 0, 0);
            a = __builtin_amdgcn_mfma_f32_16x16x32_bf16(al1, bh1, a, 0, 0, 0);
            acc[t] = a;
        }
        // C/D layout: col = lane&15, row = quad*4 + reg
        if (st < 17) {
#pragma unroll
            for (int t = 0; t < 4; ++t)
#pragma unroll
                for (int r = 0; r < 4; ++r) {
                    int row = quad * 4 + r;
                    if (row < TM)
                        Pt[row * LSTR + st * 64 + t * 16 + lr] = acc[t][r];
                }
        } else {
#pragma unroll
            for (int t = 0; t < 4; ++t)
#pragma unroll
                for (int r = 0; r < 4; ++r) {
                    int row = quad * 4 + r;
                    int gn = n0 + row;
                    if (row < TM && gn < NN)
                        ProotOut[(size_t)gn * 64 + t * 16 + lr] = acc[t][r];
                }
        }
    }
    __syncthreads();

    // ---- edge phase: contiguous per-wave slot sub-ranges, atomic agg ----
    int nend = n0 + TM; if (nend > NN) nend = NN;
    int tmeff = nend - n0;
    int r0 = rb[0], r1 = rb[tmeff];
    int total = r1 - r0;
    if (total <= 0) return;
    int per = (total + 7) >> 3;
    int s0 = r0 + w * per;
    int s1 = s0 + per; if (s1 > r1) s1 = r1;
    for (int ln = 0; ln < tmeff && s0 < s1; ++ln) {
        int lo = s0 > rb[ln] ? s0 : rb[ln];
        int hi = s1 < rb[ln + 1] ? s1 : rb[ln + 1];
        if (lo >= hi) continue;
        float p[17];
        const float* Pr = &Pt[ln * LSTR];
#pragma unroll
        for (int k = 0; k < 17; ++k) p[k] = Pr[k * 64 + l];
        for (int s = lo; s < hi; ++s) {
            int su = __builtin_amdgcn_readfirstlane(s);
            const float* er = eks + (size_t)su * 16;
            f32x4 e0 = *(const f32x4*)(er);
            f32x4 e1 = *(const f32x4*)(er + 4);
            f32x4 e2 = *(const f32x4*)(er + 8);
            f32x4 e3 = *(const f32x4*)(er + 12);
            int d = dsts[su];
            float ma = p[16], mb = 0.f;   // two chains for ILP
            ma = fmaf(e0[0], p[0], ma);  mb = fmaf(e0[1], p[1], mb);
            ma = fmaf(e0[2], p[2], ma);  mb = fmaf(e0[3], p[3], mb);
            ma = fmaf(e1[0], p[4], ma);  mb = fmaf(e1[1], p[5], mb);
            ma = fmaf(e1[2], p[6], ma);  mb = fmaf(e1[3], p[7], mb);
            ma = fmaf(e2[0], p[8], ma);  mb = fmaf(e2[1], p[9], mb);
            ma = fmaf(e2[2], p[10], ma); mb = fmaf(e2[3], p[11], mb);
            ma = fmaf(e3[0], p[12], ma); mb = fmaf(e3[1], p[13], mb);
            ma = fmaf(e3[2], p[14], ma); mb = fmaf(e3[3], p[15], mb);
            atomicAdd(&aggOut[(size_t)d * 64 + l], ma + mb);
        }
    }
}

// ---------------- out: final epilogue + fc2 dot ----------------
__global__ __launch_bounds__(256) void out_kernel(
    const float* __restrict__ agg, const float* __restrict__ Proot,
    const float* __restrict__ invd, const float* __restrict__ convb,
    const float* __restrict__ fc2_w, const float* __restrict__ fc2_b,
    float* __restrict__ out)
{
    int n = blockIdx.x * 4 + (threadIdx.x >> 6);
    int l = threadIdx.x & 63;
    float v = fmaf(agg[(size_t)n * 64 + l], invd[n],
                   Proot[(size_t)n * 64 + l] + convb[l]);
    v = fmaxf(v, 0.f) * fc2_w[l];
#pragma unroll
    for (int off = 32; off > 0; off >>= 1) v += __shfl_down(v, off);
    if (l == 0) out[n] = v + fc2_b[0];
}

extern "C" void kernel_launch(void* const* d_in, const int* in_sizes, int n_in,
                              void* d_out, int out_size, void* d_ws, size_t ws_size,
                              hipStream_t stream)
{
    const float* x         = (const float*)d_in[0];
    const int*   ei        = (const int*)  d_in[1];
    const float* edge_attr = (const float*)d_in[2];
    const float* fc1_w     = (const float*)d_in[3];
    const float* fc1_b     = (const float*)d_in[4];
    const float* k1_w      = (const float*)d_in[5];
    const float* k1_b      = (const float*)d_in[6];
    const float* k2_w      = (const float*)d_in[7];
    const float* k2_b      = (const float*)d_in[8];
    const float* root_w    = (const float*)d_in[9];
    const float* conv_b    = (const float*)d_in[10];
    const float* fc2_w     = (const float*)d_in[11];
    const float* fc2_b     = (const float*)d_in[12];
    float* out = (float*)d_out;

    // workspace layout, f32 units
    float* ws = (float*)d_ws;
    size_t off = 0;
    int* cnt   = (int*)(ws + off); off += 3 * NN;       // outc|inc|fs
    int* outc  = cnt;
    int* inc   = cnt + NN;
    int* fs    = cnt + 2 * NN;
    int* rps   = (int*)(ws + off); off += 20004;
    int* partials = (int*)(ws + off); off += 64;
    int* bases    = (int*)(ws + off); off += 64;
    int* dsts  = (int*)(ws + off); off += NE;
    float* invd  = ws + off; off += NN;
    float* eks   = ws + off; off += (size_t)NE * 16;
    unsigned short* Gh  = (unsigned short*)(ws + off); off += 36864;
    unsigned short* Gl  = (unsigned short*)(ws + off); off += 36864;
    float* aggA   = ws + off; off += (size_t)NN * WD;
    float* aggB   = ws + off; off += (size_t)NN * WD;
    float* ProotA = ws + off; off += (size_t)NN * WD;
    float* ProotB = ws + off; off += (size_t)NN * WD;

    hipMemsetAsync(cnt, 0, 3 * NN * sizeof(int), stream);
    count_kernel<<<(NE + 255) / 256, 256, 0, stream>>>(ei, outc, inc);
    scanA_kernel<<<40, 256, 0, stream>>>(cnt, partials);
    scanB_kernel<<<1, 64, 0, stream>>>(partials, bases);
    scanC_kernel<<<40, 256, 0, stream>>>(cnt, bases, rps, invd);
    ekfill_kernel<<<(NE + 255) / 256, 256, 0, stream>>>(ei, edge_attr, k1_w, k1_b,
                                                        rps, fs, eks, dsts);
    gwt_kernel<<<(1152 * 64 + 255) / 256, 256, 0, stream>>>(k2_w, k2_b, root_w, Gh, Gl);

    int ntiles = (NN + TM - 1) / TM;   // 1334
    float* aggIn = aggB;   float* aggOut = aggA;
    float* prIn  = ProotB; float* prOut  = ProotA;
    for (int layer = 0; layer < DEPTH; ++layer) {
        hipMemsetAsync(aggOut, 0, (size_t)NN * WD * sizeof(float), stream);
        fused_kernel<<<ntiles, 512, 0, stream>>>(x, fc1_w, fc1_b,
                                                 aggIn, prIn, invd, conv_b,
                                                 Gh, Gl, eks, dsts, rps,
                                                 prOut, aggOut, layer == 0 ? 1 : 0);
        float* t;
        t = aggIn; aggIn = aggOut; aggOut = t;
        t = prIn;  prIn  = prOut;  prOut  = t;
    }

    // final state: aggIn / prIn hold layer-5 outputs
    out_kernel<<<NN / 4, 256, 0, stream>>>(aggIn, prIn, invd, conv_b,
                                           fc2_w, fc2_b, out);
}